// Round 3
// baseline (48.803 us; speedup 1.0000x reference)
//
#include <hip/hip_runtime.h>

#define IN_DIM     4288   // 64*64 + 8*24
#define LOGITS_DIM 4096
#define PP_DIM     192
#define OUT_DIM    1858
#define PADDED_OUT 2048   // padded so per-thread u<8 pair loads need no guard
#define MAXNZ      8      // general-correctness bound on nonzeros per column
#define OVF        (MAXNZ - 1)

// workspace word layout:
//   cnt[OUT_DIM] | flag @ w[OUT_DIM] | pad @ w[OUT_DIM+1]
//   pair[PADDED_OUT] (int2, starts at word 1860 -> 8B aligned)
//   idxo[OUT_DIM*OVF] | valo[OUT_DIM*OVF]   (NOT pre-zeroed; slow path uses cnt)
#define PAIR_OFF   (OUT_DIM + 2)                    // 1860 words
#define ZERO_WORDS (PAIR_OFF + 2 * PADDED_OUT)      // cnt+flag+pair region

// --- kernel 1: zero cnt, flag, and pair region (ws is poisoned 0xAA) ---
__global__ void zero_ws_kernel(int* __restrict__ w) {
    int t = blockIdx.x * blockDim.x + threadIdx.x;
    if (t < ZERO_WORDS) w[t] = 0;
}

// --- kernel 2: build zero-padded sparse rep of fc1 ---
// Slot 0 -> packed pair[j] = {row index, value bits}; slots 1..MAXNZ-1 ->
// overflow arrays + flag (uniform slow path). Actual data: 1 nz/col, flag=0.
__global__ void build_csc_kernel(const float* __restrict__ fc1,
                                 int* __restrict__ cnt,
                                 int* __restrict__ flag,
                                 int2* __restrict__ pair,
                                 int* __restrict__ idxo,
                                 float* __restrict__ valo) {
    const long total4 = (long)IN_DIM * OUT_DIM / 4;
    const long stride = (long)gridDim.x * blockDim.x;
    for (long t = blockIdx.x * (long)blockDim.x + threadIdx.x; t < total4; t += stride) {
        float4 v = ((const float4*)fc1)[t];
        float vv[4] = {v.x, v.y, v.z, v.w};
        #pragma unroll
        for (int c = 0; c < 4; ++c) {
            if (vv[c] != 0.0f) {
                long e = t * 4 + c;
                int j = (int)(e % OUT_DIM);   // column (fc1 is [IN_DIM][OUT_DIM] row-major)
                int i = (int)(e / OUT_DIM);   // row = input index
                int slot = atomicAdd(&cnt[j], 1);
                if (slot == 0) {
                    pair[j] = make_int2(i, __float_as_int(vv[c]));
                } else if (slot < MAXNZ) {
                    idxo[j * OVF + slot - 1] = i;
                    valo[j * OVF + slot - 1] = vv[c];
                    *flag = 1;
                }
            }
        }
    }
}

// --- kernel 3: per-batch-row gather through LDS, fully unrolled fast path ---
__global__ __launch_bounds__(256) void gather_kernel(
        const float* __restrict__ logits,
        const float* __restrict__ pp,
        const int*   __restrict__ flag,
        const int2*  __restrict__ pair,
        const int*   __restrict__ cnt,
        const int*   __restrict__ idxo,
        const float* __restrict__ valo,
        float*       __restrict__ out) {
    __shared__ float row[IN_DIM];
    const int b   = blockIdx.x;
    const int tid = threadIdx.x;

    // stage the 4288-float input row: 4 float4/thread (logits) + pp tail
    const float4* lg4 = (const float4*)(logits + (size_t)b * LOGITS_DIM);
    float4* row4 = (float4*)row;
    #pragma unroll
    for (int u = 0; u < 4; ++u)
        row4[tid + u * 256] = lg4[tid + u * 256];
    if (tid < PP_DIM / 4)
        ((float4*)(row + LOGITS_DIM))[tid] =
            ((const float4*)(pp + (size_t)b * PP_DIM))[tid];

    // hoist this thread's 8 packed (idx,val) pairs into registers (dwordx2
    // loads, all independent, overlap the staging); padded -> no guard
    int2 rp[8];
    #pragma unroll
    for (int u = 0; u < 8; ++u)
        rp[u] = pair[tid + u * 256];
    const int of = *flag;   // wave-uniform

    __syncthreads();

    float* orow = out + (size_t)b * OUT_DIM;
    if (of == 0) {
        // fast path: 8 independent LDS gathers + fmuls; nontemporal stores so
        // the 61 MB output stream doesn't evict inputs/fc1 from L3
        #pragma unroll
        for (int u = 0; u < 8; ++u) {
            int j = tid + u * 256;
            if (j < OUT_DIM)
                __builtin_nontemporal_store(
                    __int_as_float(rp[u].y) * row[rp[u].x], &orow[j]);
        }
    } else {
        // general path: runtime count over overflow slots (never taken for
        // the actual one-hot map; kept for general fc1 up to MAXNZ nz/col)
        #pragma unroll
        for (int u = 0; u < 8; ++u) {
            int j = tid + u * 256;
            if (j < OUT_DIM) {
                float acc = __int_as_float(rp[u].y) * row[rp[u].x];
                int c = cnt[j];
                c = (c > MAXNZ ? MAXNZ : c) - 1;
                for (int k = 0; k < c; ++k)
                    acc += valo[j * OVF + k] * row[idxo[j * OVF + k]];
                __builtin_nontemporal_store(acc, &orow[j]);
            }
        }
    }
}

extern "C" void kernel_launch(void* const* d_in, const int* in_sizes, int n_in,
                              void* d_out, int out_size, void* d_ws, size_t ws_size,
                              hipStream_t stream) {
    const float* logits = (const float*)d_in[0];   // [B, 64, 64] f32
    const float* pp     = (const float*)d_in[1];   // [B, 8, 24] f32
    const float* fc1    = (const float*)d_in[2];   // [4288, 1858] f32
    float* out = (float*)d_out;                    // [B, 1858] f32

    const int B = in_sizes[0] / LOGITS_DIM;        // 8192

    int*   w    = (int*)d_ws;
    int*   cnt  = w;
    int*   flag = w + OUT_DIM;
    int2*  pair = (int2*)(w + PAIR_OFF);
    int*   idxo = (int*)(pair + PADDED_OUT);
    float* valo = (float*)(idxo + OUT_DIM * OVF);

    zero_ws_kernel<<<(ZERO_WORDS + 255) / 256, 256, 0, stream>>>(w);
    build_csc_kernel<<<1024, 256, 0, stream>>>(fc1, cnt, flag, pair, idxo, valo);
    gather_kernel<<<B, 256, 0, stream>>>(logits, pp, flag, pair, cnt, idxo, valo, out);
}

// Round 4
// 45.667 us; speedup vs baseline: 1.0687x; 1.0687x over previous
//
#include <hip/hip_runtime.h>

#define IN_DIM     4288   // 64*64 + 8*24
#define LOGITS_DIM 4096
#define PP_DIM     192
#define OUT_DIM    1858
#define PADDED_OUT 2048   // padded so unguarded pair loads stay in-bounds
#define MAXNZ      8      // general-correctness bound on nonzeros per column
#define OVF        (MAXNZ - 1)
#define OUT_G      (OUT_DIM / 4)          // 464 full float4 output groups
#define OUT_TAIL   (OUT_DIM - OUT_G * 4)  // 2 tail elements

// workspace word layout:
//   cnt[OUT_DIM] | flag @ w[OUT_DIM] | pad to 16B
//   pair[PADDED_OUT] (int2, 16B-aligned)
//   idxo[OUT_DIM*OVF] | valo[OUT_DIM*OVF]   (NOT pre-zeroed; slow path uses cnt)
#define PAIR_OFF   1864                         // words; 1864*4 = 7456 = 16B-aligned
#define ZERO_WORDS (PAIR_OFF + 2 * PADDED_OUT)  // cnt+flag+pair region

// --- kernel 1: zero cnt, flag, and pair region (ws is poisoned 0xAA) ---
__global__ void zero_ws_kernel(int* __restrict__ w) {
    int t = blockIdx.x * blockDim.x + threadIdx.x;
    if (t < ZERO_WORDS) w[t] = 0;
}

// --- kernel 2: build zero-padded sparse rep of fc1 ---
// Slot 0 -> packed pair[j] = {row index, value bits}; slots 1..MAXNZ-1 ->
// overflow arrays + flag (uniform slow path). Actual data: 1 nz/col, flag=0.
__global__ void build_csc_kernel(const float* __restrict__ fc1,
                                 int* __restrict__ cnt,
                                 int* __restrict__ flag,
                                 int2* __restrict__ pair,
                                 int* __restrict__ idxo,
                                 float* __restrict__ valo) {
    const long total4 = (long)IN_DIM * OUT_DIM / 4;
    const long stride = (long)gridDim.x * blockDim.x;
    for (long t = blockIdx.x * (long)blockDim.x + threadIdx.x; t < total4; t += stride) {
        float4 v = ((const float4*)fc1)[t];
        float vv[4] = {v.x, v.y, v.z, v.w};
        #pragma unroll
        for (int c = 0; c < 4; ++c) {
            if (vv[c] != 0.0f) {
                long e = t * 4 + c;
                int j = (int)(e % OUT_DIM);   // column (fc1 is [IN_DIM][OUT_DIM] row-major)
                int i = (int)(e / OUT_DIM);   // row = input index
                int slot = atomicAdd(&cnt[j], 1);
                if (slot == 0) {
                    pair[j] = make_int2(i, __float_as_int(vv[c]));
                } else if (slot < MAXNZ) {
                    idxo[j * OVF + slot - 1] = i;
                    valo[j * OVF + slot - 1] = vv[c];
                    *flag = 1;
                }
            }
        }
    }
}

// --- kernel 3: per-batch-row gather through LDS ---
// Staging via global_load_lds (direct HBM->LDS, no VGPR round trip);
// outputs packed 4 consecutive j per thread -> dwordx4 loads and stores.
__global__ __launch_bounds__(256) void gather_kernel(
        const float* __restrict__ logits,
        const float* __restrict__ pp,
        const int*   __restrict__ flag,
        const int2*  __restrict__ pair,
        const int*   __restrict__ cnt,
        const int*   __restrict__ idxo,
        const float* __restrict__ valo,
        float*       __restrict__ out) {
    __shared__ float row[IN_DIM];
    const int b   = blockIdx.x;
    const int tid = threadIdx.x;

    // stage the 4288-float input row straight into LDS, 16B per lane.
    // LDS dest is contiguous in lane order (wave-uniform base + lane*16) -> legal.
    const float4* lg4  = (const float4*)(logits + (size_t)b * LOGITS_DIM);
    float4*       row4 = (float4*)row;
    #pragma unroll
    for (int u = 0; u < 4; ++u) {
        __builtin_amdgcn_global_load_lds(
            (const __attribute__((address_space(1))) void*)(lg4 + tid + u * 256),
            (__attribute__((address_space(3))) void*)(row4 + tid + u * 256),
            16, 0, 0);
    }
    if (tid < PP_DIM / 4) {
        __builtin_amdgcn_global_load_lds(
            (const __attribute__((address_space(1))) void*)(((const float4*)(pp + (size_t)b * PP_DIM)) + tid),
            (__attribute__((address_space(3))) void*)(((float4*)(row + LOGITS_DIM)) + tid),
            16, 0, 0);
    }

    // hoist this thread's 8 (idx,val) pairs (two dwordx4 per group of 4 j's)
    // into registers while the gload_lds queue drains
    int4 rp01[2], rp23[2];
    #pragma unroll
    for (int u = 0; u < 2; ++u) {
        int g = tid + u * 256;               // float4 output group, g < 512
        rp01[u] = ((const int4*)pair)[2 * g];
        rp23[u] = ((const int4*)pair)[2 * g + 1];
    }
    const int of = *flag;   // wave-uniform

    __syncthreads();        // drains vmcnt -> LDS row complete

    float* orow = out + (size_t)b * OUT_DIM;
    if (of == 0) {
        // fast path: 8 LDS gathers, 2 float4 stores (+2-elem tail)
        #pragma unroll
        for (int u = 0; u < 2; ++u) {
            int g = tid + u * 256;
            if (g < OUT_G) {
                float4 o;
                o.x = __int_as_float(rp01[u].y) * row[rp01[u].x];
                o.y = __int_as_float(rp01[u].w) * row[rp01[u].z];
                o.z = __int_as_float(rp23[u].y) * row[rp23[u].x];
                o.w = __int_as_float(rp23[u].w) * row[rp23[u].z];
                ((float4*)orow)[g] = o;
            } else if (g == OUT_G) {
                orow[4 * g]     = __int_as_float(rp01[u].y) * row[rp01[u].x];
                orow[4 * g + 1] = __int_as_float(rp01[u].w) * row[rp01[u].z];
            }
        }
    } else {
        // general path: runtime count over overflow slots (never taken for
        // the actual one-hot map; kept correct for general fc1 <= MAXNZ nz/col)
        #pragma unroll
        for (int u = 0; u < 2; ++u) {
            int g = tid + u * 256;
            int jv[4] = {rp01[u].x, rp01[u].z, rp23[u].x, rp23[u].z};
            int vv[4] = {rp01[u].y, rp01[u].w, rp23[u].y, rp23[u].w};
            #pragma unroll
            for (int e = 0; e < 4; ++e) {
                int j = 4 * g + e;
                if (j < OUT_DIM) {
                    float acc = __int_as_float(vv[e]) * row[jv[e]];
                    int c = cnt[j];
                    c = (c > MAXNZ ? MAXNZ : c) - 1;
                    for (int k = 0; k < c; ++k)
                        acc += valo[j * OVF + k] * row[idxo[j * OVF + k]];
                    orow[j] = acc;
                }
            }
        }
    }
}

extern "C" void kernel_launch(void* const* d_in, const int* in_sizes, int n_in,
                              void* d_out, int out_size, void* d_ws, size_t ws_size,
                              hipStream_t stream) {
    const float* logits = (const float*)d_in[0];   // [B, 64, 64] f32
    const float* pp     = (const float*)d_in[1];   // [B, 8, 24] f32
    const float* fc1    = (const float*)d_in[2];   // [4288, 1858] f32
    float* out = (float*)d_out;                    // [B, 1858] f32

    const int B = in_sizes[0] / LOGITS_DIM;        // 8192

    int*   w    = (int*)d_ws;
    int*   cnt  = w;
    int*   flag = w + OUT_DIM;
    int2*  pair = (int2*)(w + PAIR_OFF);
    int*   idxo = (int*)(pair + PADDED_OUT);
    float* valo = (float*)(idxo + OUT_DIM * OVF);

    zero_ws_kernel<<<(ZERO_WORDS + 255) / 256, 256, 0, stream>>>(w);
    build_csc_kernel<<<1024, 256, 0, stream>>>(fc1, cnt, flag, pair, idxo, valo);
    gather_kernel<<<B, 256, 0, stream>>>(logits, pp, flag, pair, cnt, idxo, valo, out);
}